// Round 1
// baseline (387.815 us; speedup 1.0000x reference)
//
#include <hip/hip_runtime.h>

// RoI Align 14x14, bilinear, spatial_scale = 0.0625.
// features: (N=2, C=512, H=100, W=152) fp32 NCHW
// rois:     (R=512, 5) fp32
// out:      (R, 512, 14, 14) fp32
//
// v2: NCHW -> NHWC transpose (float4 both sides), then channel-quad-coalesced
// gather (lane = 4 channels via float4 loads, 256 ch/block), output transposed
// back to NCHW via LDS in 7 passes of 28 bins with float4 stores.

#define AH 14
#define AW 14
#define NB (AH * AW)            // 196

constexpr int Nn  = 2;
constexpr int Cc  = 512;
constexpr int Hh  = 100;
constexpr int Ww  = 152;
constexpr int HW  = Hh * Ww;    // 15200

constexpr int CPB2 = 256;       // channels per block (64 lanes x float4)
constexpr int BPP  = 28;        // bins per pass (divisible by 4)
constexpr int NPASS = NB / BPP; // 7
constexpr int TS   = 260;       // tile row stride in floats (28 rows x 260)

// ---------------------------------------------------------------- transpose
// Per batch: A[C][HW] -> B[HW][C], 64x64 tiles via LDS, float4 global I/O.
__global__ __launch_bounds__(256)
void nchw_to_nhwc(const float* __restrict__ feat, float* __restrict__ nhwc)
{
    __shared__ float tile[64][65];

    const int n  = blockIdx.z;
    const int s0 = blockIdx.x * 64;
    const int c0 = blockIdx.y * 64;
    const int q  = (threadIdx.x & 15) * 4;   // quad offset 0..60
    const int g  = threadIdx.x >> 4;         // 0..15

    const float* A = feat + (size_t)n * Cc * HW;
    float*       B = nhwc + (size_t)n * HW * Cc;

    // load: rows = channels, float4 along spatial
    if (s0 + q < HW) {                        // HW % 4 == 0 -> whole quad in
        #pragma unroll
        for (int i = 0; i < 4; ++i) {
            const int cl = g + 16 * i;        // 0..63
            const float4 v = *(const float4*)&A[(size_t)(c0 + cl) * HW + (s0 + q)];
            tile[cl][q + 0] = v.x;
            tile[cl][q + 1] = v.y;
            tile[cl][q + 2] = v.z;
            tile[cl][q + 3] = v.w;
        }
    }
    __syncthreads();
    // store: rows = spatial, float4 along channel
    #pragma unroll
    for (int i = 0; i < 4; ++i) {
        const int sl = g + 16 * i;            // 0..63
        if (s0 + sl < HW) {
            float4 v;
            v.x = tile[q + 0][sl];
            v.y = tile[q + 1][sl];
            v.z = tile[q + 2][sl];
            v.w = tile[q + 3][sl];
            *(float4*)&B[(size_t)(s0 + sl) * Cc + (c0 + q)] = v;
        }
    }
}

// ---------------------------------------------------------------- main
__global__ __launch_bounds__(256)
void roi_align_nhwc(const float* __restrict__ nhwc,
                    const float* __restrict__ rois,
                    float* __restrict__ out)
{
    const int r    = blockIdx.x;
    const int c0   = blockIdx.y * CPB2;       // 0 or 256
    const int tid  = threadIdx.x;
    const int lane = tid & 63;
    const int wid  = tid >> 6;

    __shared__ int4   s_off[NB];              // neighbor offsets in float4 units
    __shared__ float4 s_w[NB];
    __shared__ int    s_base;                 // batch base in floats
    __shared__ float  tile[BPP * TS];         // [bin_local][channel], 29.1 KB

    const float* roi = rois + r * 5;
    const float x_start = roi[1] * 0.0625f;
    const float y_start = roi[2] * 0.0625f;
    const float roi_w = fmaxf(roi[3] * 0.0625f - x_start, 0.0f);
    const float roi_h = fmaxf(roi[4] * 0.0625f - y_start, 0.0f);
    const float bin_h = roi_h / (float)(AH - 1);
    const float bin_w = roi_w / (float)(AW - 1);

    if (tid == 0)
        s_base = ((int)roi[0]) * (HW * Cc);

    if (tid < NB) {
        const int ph = tid / AW;
        const int pw = tid - ph * AW;
        float ys = y_start + (float)ph * bin_h;
        float xs = x_start + (float)pw * bin_w;
        ys = fminf(fmaxf(ys, 0.0f), (float)(Hh - 1));
        xs = fminf(fmaxf(xs, 0.0f), (float)(Ww - 1));
        const int y0 = (int)floorf(ys);
        const int x0 = (int)floorf(xs);
        const int y1 = min(y0 + 1, Hh - 1);
        const int x1 = min(x0 + 1, Ww - 1);
        const float wy = ys - (float)y0;
        const float wx = xs - (float)x0;
        // float4-unit offsets: pixel * (512/4) = pixel << 7
        s_off[tid] = make_int4((y0 * Ww + x0) << 7, (y0 * Ww + x1) << 7,
                               (y1 * Ww + x0) << 7, (y1 * Ww + x1) << 7);
        s_w[tid]   = make_float4((1.0f - wy) * (1.0f - wx),
                                 (1.0f - wy) * wx,
                                 wy * (1.0f - wx),
                                 wy * wx);
    }
    __syncthreads();

    // lane handles channels c0 + 4*lane .. +3
    const float4* __restrict__ fb = (const float4*)(nhwc + s_base + c0) + lane;
    float* __restrict__ outr = out + (size_t)r * (Cc * NB) + (size_t)c0 * NB;

    for (int pass = 0; pass < NPASS; ++pass) {
        // compute: wave handles bins pass*28 + {wid, wid+4, ...} (7 iters)
        #pragma unroll 2
        for (int bl = wid; bl < BPP; bl += 4) {
            const int bin = pass * BPP + bl;
            const int4   o = s_off[bin];
            const float4 w = s_w[bin];
            const float4 p0 = fb[o.x];
            const float4 p1 = fb[o.y];
            const float4 p2 = fb[o.z];
            const float4 p3 = fb[o.w];
            float4 v;
            v.x = w.x * p0.x + w.y * p1.x + w.z * p2.x + w.w * p3.x;
            v.y = w.x * p0.y + w.y * p1.y + w.z * p2.y + w.w * p3.y;
            v.z = w.x * p0.z + w.y * p1.z + w.z * p2.z + w.w * p3.z;
            v.w = w.x * p0.w + w.y * p1.w + w.z * p2.w + w.w * p3.w;
            *(float4*)&tile[bl * TS + lane * 4] = v;    // 16B-aligned b128
        }
        __syncthreads();
        // write back NCHW: 28*256 floats = 1792 float4 = 7 per thread
        #pragma unroll
        for (int k = 0; k < 7; ++k) {
            const int fidx = k * 256 + tid;             // 0..1791
            const int cl   = fidx / 7;                  // channel 0..255
            const int rem  = fidx - cl * 7;             // bin quad 0..6
            float4 v;
            v.x = tile[(rem * 4 + 0) * TS + cl];
            v.y = tile[(rem * 4 + 1) * TS + cl];
            v.z = tile[(rem * 4 + 2) * TS + cl];
            v.w = tile[(rem * 4 + 3) * TS + cl];
            *(float4*)&outr[cl * NB + pass * BPP + rem * 4] = v;
        }
        __syncthreads();
    }
}

// ---------------------------------------------------------------- fallback
// (used only if workspace is too small for the NHWC copy)
__global__ __launch_bounds__(256)
void roi_align_nchw(const float* __restrict__ feat,
                    const float* __restrict__ rois,
                    float* __restrict__ out)
{
    const int r  = blockIdx.x;
    const int c0 = blockIdx.y * 128;

    __shared__ int4   s_off[NB];
    __shared__ float4 s_w[NB];
    __shared__ int    s_base;

    const float* roi = rois + r * 5;
    const float x_start = roi[1] * 0.0625f;
    const float y_start = roi[2] * 0.0625f;
    const float roi_w = fmaxf(roi[3] * 0.0625f - x_start, 0.0f);
    const float roi_h = fmaxf(roi[4] * 0.0625f - y_start, 0.0f);
    const float bin_h = roi_h / (float)(AH - 1);
    const float bin_w = roi_w / (float)(AW - 1);

    if (threadIdx.x == 0)
        s_base = ((int)roi[0]) * (Cc * HW);

    for (int i = threadIdx.x; i < NB; i += blockDim.x) {
        const int ph = i / AW;
        const int pw = i - ph * AW;
        float ys = y_start + (float)ph * bin_h;
        float xs = x_start + (float)pw * bin_w;
        ys = fminf(fmaxf(ys, 0.0f), (float)(Hh - 1));
        xs = fminf(fmaxf(xs, 0.0f), (float)(Ww - 1));
        const int y0 = (int)floorf(ys);
        const int x0 = (int)floorf(xs);
        const int y1 = min(y0 + 1, Hh - 1);
        const int x1 = min(x0 + 1, Ww - 1);
        const float wy = ys - (float)y0;
        const float wx = xs - (float)x0;
        s_off[i] = make_int4(y0 * Ww + x0, y0 * Ww + x1,
                             y1 * Ww + x0, y1 * Ww + x1);
        s_w[i]   = make_float4((1.0f - wy) * (1.0f - wx),
                               (1.0f - wy) * wx,
                               wy * (1.0f - wx),
                               wy * wx);
    }
    __syncthreads();

    const int base = s_base;
    float* __restrict__ outr = out + (size_t)r * (Cc * NB);
    const int jend = (c0 + 128) * NB;
    for (int j = c0 * NB + (int)threadIdx.x * 4; j < jend; j += 256 * 4) {
        const int c   = j / NB;
        const int bin = j - c * NB;
        const float* f = feat + base + c * HW;
        float4 v;
        {
            const int4 o = s_off[bin];     const float4 w = s_w[bin];
            v.x = w.x*f[o.x] + w.y*f[o.y] + w.z*f[o.z] + w.w*f[o.w];
        }
        {
            const int4 o = s_off[bin + 1]; const float4 w = s_w[bin + 1];
            v.y = w.x*f[o.x] + w.y*f[o.y] + w.z*f[o.z] + w.w*f[o.w];
        }
        {
            const int4 o = s_off[bin + 2]; const float4 w = s_w[bin + 2];
            v.z = w.x*f[o.x] + w.y*f[o.y] + w.z*f[o.z] + w.w*f[o.w];
        }
        {
            const int4 o = s_off[bin + 3]; const float4 w = s_w[bin + 3];
            v.w = w.x*f[o.x] + w.y*f[o.y] + w.z*f[o.z] + w.w*f[o.w];
        }
        *(float4*)(outr + j) = v;
    }
}

extern "C" void kernel_launch(void* const* d_in, const int* in_sizes, int n_in,
                              void* d_out, int out_size, void* d_ws, size_t ws_size,
                              hipStream_t stream)
{
    const float* feat = (const float*)d_in[0];
    const float* rois = (const float*)d_in[1];
    float*       out  = (float*)d_out;
    const int R = in_sizes[1] / 5;                       // 512

    const size_t need = (size_t)Nn * HW * Cc * sizeof(float);   // 62.26 MB
    if (ws_size >= need) {
        float* nhwc = (float*)d_ws;
        dim3 tg((HW + 63) / 64, Cc / 64, Nn);            // (238, 8, 2)
        nchw_to_nhwc<<<tg, 256, 0, stream>>>(feat, nhwc);
        dim3 mg(R, Cc / CPB2);                           // (512, 2)
        roi_align_nhwc<<<mg, 256, 0, stream>>>(nhwc, rois, out);
    } else {
        dim3 grid(R, Cc / 128);
        roi_align_nchw<<<grid, 256, 0, stream>>>(feat, rois, out);
    }
}

// Round 3
// 387.563 us; speedup vs baseline: 1.0006x; 1.0006x over previous
//
#include <hip/hip_runtime.h>
#include <hip/hip_fp16.h>

// RoI Align 14x14, bilinear, spatial_scale = 0.0625.
// features: (N=2, C=512, H=100, W=152) fp32 NCHW
// rois:     (R=512, 5) fp32
// out:      (R, 512, 14, 14) fp32
//
// v3b: NCHW fp32 -> NHWC *fp16* staging (halves the byte-bound gather stream),
// channel-quad gather (lane = 4 channels via 8B loads, fp32 accumulate),
// rotation-swizzled LDS tile for conflict-free output transpose,
// nontemporal output stores (keep fp16 NHWC hot in L2/L3).
// (v3 fix: nontemporal builtins need ext_vector_type, not HIP float4.)

#define AH 14
#define AW 14
#define NB (AH * AW)            // 196

constexpr int Nn  = 2;
constexpr int Cc  = 512;
constexpr int Hh  = 100;
constexpr int Ww  = 152;
constexpr int HW  = Hh * Ww;    // 15200

constexpr int CPB  = 256;       // channels per block (64 lanes x 4 ch)
constexpr int BPP  = 28;        // bins per pass
constexpr int NPASS = NB / BPP; // 7
constexpr int TSF  = 256;       // tile row stride in floats (= CPB, pow2, swizzled)

typedef float f32x4 __attribute__((ext_vector_type(4)));

// ---------------------------------------------------------------- transpose
// Per batch: A[C][HW] fp32 -> B[HW][C] fp16, 64x64 tiles via LDS.
__global__ __launch_bounds__(256)
void nchw_to_nhwc_f16(const float* __restrict__ feat, __half* __restrict__ nhwc)
{
    __shared__ float tile[64][65];

    const int n  = blockIdx.z;
    const int s0 = blockIdx.x * 64;
    const int c0 = blockIdx.y * 64;
    const int q  = (threadIdx.x & 15) * 4;   // spatial quad offset 0..60
    const int g  = threadIdx.x >> 4;         // 0..15

    const float* A = feat + (size_t)n * Cc * HW;
    __half*      B = nhwc + (size_t)n * HW * Cc;

    // load: rows = channels, float4 along spatial (read-once: nontemporal)
    if (s0 + q < HW) {                        // HW % 4 == 0 -> whole quad in
        #pragma unroll
        for (int i = 0; i < 4; ++i) {
            const int cl = g + 16 * i;        // 0..63
            const f32x4 v = __builtin_nontemporal_load(
                (const f32x4*)&A[(size_t)(c0 + cl) * HW + (s0 + q)]);
            tile[cl][q + 0] = v[0];
            tile[cl][q + 1] = v[1];
            tile[cl][q + 2] = v[2];
            tile[cl][q + 3] = v[3];
        }
    }
    __syncthreads();

    // store: rows = spatial, 8 channels -> 8 halves (16B) per thread
    const int c8    = (threadIdx.x & 7) * 8;  // channel octet 0..56
    const int sbase = threadIdx.x >> 3;       // 0..31
    #pragma unroll
    for (int i = 0; i < 2; ++i) {
        const int sl = sbase + 32 * i;        // 0..63
        if (s0 + sl < HW) {
            __half2 h[4];
            #pragma unroll
            for (int k = 0; k < 4; ++k)
                h[k] = __floats2half2_rn(tile[c8 + 2 * k][sl],
                                         tile[c8 + 2 * k + 1][sl]);
            *(uint4*)(B + (size_t)(s0 + sl) * Cc + c0 + c8) = *(uint4*)h;
        }
    }
}

// ---------------------------------------------------------------- main
__global__ __launch_bounds__(256)
void roi_align_nhwc_f16(const __half* __restrict__ nhwc,
                        const float* __restrict__ rois,
                        float* __restrict__ out)
{
    const int r    = blockIdx.x;
    const int cb0  = blockIdx.y * CPB;        // 0 or 256
    const int tid  = threadIdx.x;
    const int lane = tid & 63;
    const int wid  = tid >> 6;

    __shared__ int4   s_off[NB];              // neighbor offsets in uint2(4ch) units
    __shared__ float4 s_w[NB];
    __shared__ int    s_base;                 // batch base in halves
    __shared__ float  tile[BPP * TSF];        // 28.7 KB, rotation-swizzled

    const float* roi = rois + r * 5;
    const float x_start = roi[1] * 0.0625f;
    const float y_start = roi[2] * 0.0625f;
    const float roi_w = fmaxf(roi[3] * 0.0625f - x_start, 0.0f);
    const float roi_h = fmaxf(roi[4] * 0.0625f - y_start, 0.0f);
    const float bin_h = roi_h / (float)(AH - 1);
    const float bin_w = roi_w / (float)(AW - 1);

    if (tid == 0)
        s_base = ((int)roi[0]) * (HW * Cc);

    if (tid < NB) {
        const int ph = tid / AW;
        const int pw = tid - ph * AW;
        float ys = y_start + (float)ph * bin_h;
        float xs = x_start + (float)pw * bin_w;
        ys = fminf(fmaxf(ys, 0.0f), (float)(Hh - 1));
        xs = fminf(fmaxf(xs, 0.0f), (float)(Ww - 1));
        const int y0 = (int)floorf(ys);
        const int x0 = (int)floorf(xs);
        const int y1 = min(y0 + 1, Hh - 1);
        const int x1 = min(x0 + 1, Ww - 1);
        const float wy = ys - (float)y0;
        const float wx = xs - (float)x0;
        // uint2-unit offsets: pixel * (512ch / 4ch-per-uint2) = pixel << 7
        s_off[tid] = make_int4((y0 * Ww + x0) << 7, (y0 * Ww + x1) << 7,
                               (y1 * Ww + x0) << 7, (y1 * Ww + x1) << 7);
        s_w[tid]   = make_float4((1.0f - wy) * (1.0f - wx),
                                 (1.0f - wy) * wx,
                                 wy * (1.0f - wx),
                                 wy * wx);
    }
    __syncthreads();

    // lane handles channels cb0 + 4*lane .. +3 (one uint2 = 4 halves per tap)
    const uint2* __restrict__ fb = (const uint2*)(nhwc + s_base + cb0) + lane;
    float* __restrict__ outr = out + (size_t)r * (Cc * NB) + (size_t)cb0 * NB;

    for (int pass = 0; pass < NPASS; ++pass) {
        // compute: wave handles bins pass*28 + {wid, wid+4, ...} (7 iters)
        #pragma unroll 2
        for (int bl = wid; bl < BPP; bl += 4) {
            const int bin = pass * BPP + bl;
            const int4   o = s_off[bin];
            const float4 w = s_w[bin];
            const uint2 pa = fb[o.x];
            const uint2 pb = fb[o.y];
            const uint2 pc = fb[o.z];
            const uint2 pd = fb[o.w];
            const float2 a0 = __half22float2(*(const __half2*)&pa.x);
            const float2 a1 = __half22float2(*(const __half2*)&pa.y);
            const float2 b0 = __half22float2(*(const __half2*)&pb.x);
            const float2 b1 = __half22float2(*(const __half2*)&pb.y);
            const float2 c0 = __half22float2(*(const __half2*)&pc.x);
            const float2 c1 = __half22float2(*(const __half2*)&pc.y);
            const float2 d0 = __half22float2(*(const __half2*)&pd.x);
            const float2 d1 = __half22float2(*(const __half2*)&pd.y);
            f32x4 v;
            v[0] = w.x * a0.x + w.y * b0.x + w.z * c0.x + w.w * d0.x;
            v[1] = w.x * a0.y + w.y * b0.y + w.z * c0.y + w.w * d0.y;
            v[2] = w.x * a1.x + w.y * b1.x + w.z * c1.x + w.w * d1.x;
            v[3] = w.x * a1.y + w.y * b1.y + w.z * c1.y + w.w * d1.y;
            // rotation swizzle: slot = (lane + row/4) & 63 -> conflict-free
            // b128 write now AND spreads readback rows across bank quads.
            const int slot = (lane + (bl >> 2)) & 63;
            *(f32x4*)&tile[bl * TSF + slot * 4] = v;
        }
        __syncthreads();
        // write back NCHW: 28*256 floats = 1792 float4 = 7 per thread
        #pragma unroll
        for (int k = 0; k < 7; ++k) {
            const int fidx = k * 256 + tid;             // 0..1791
            const int cl   = fidx / 7;                  // channel 0..255
            const int rem  = fidx - cl * 7;             // bin quad 0..6
            const int slot = ((cl >> 2) + rem) & 63;    // matches write swizzle
            const int e    = cl & 3;
            f32x4 v;
            v[0] = tile[(rem * 4 + 0) * TSF + slot * 4 + e];
            v[1] = tile[(rem * 4 + 1) * TSF + slot * 4 + e];
            v[2] = tile[(rem * 4 + 2) * TSF + slot * 4 + e];
            v[3] = tile[(rem * 4 + 3) * TSF + slot * 4 + e];
            __builtin_nontemporal_store(v,
                (f32x4*)&outr[cl * NB + pass * BPP + rem * 4]);
        }
        __syncthreads();
    }
}

// ---------------------------------------------------------------- fallback
// (used only if workspace is too small for the NHWC fp16 copy)
__global__ __launch_bounds__(256)
void roi_align_nchw(const float* __restrict__ feat,
                    const float* __restrict__ rois,
                    float* __restrict__ out)
{
    const int r  = blockIdx.x;
    const int c0 = blockIdx.y * 128;

    __shared__ int4   s_off[NB];
    __shared__ float4 s_w[NB];
    __shared__ int    s_base;

    const float* roi = rois + r * 5;
    const float x_start = roi[1] * 0.0625f;
    const float y_start = roi[2] * 0.0625f;
    const float roi_w = fmaxf(roi[3] * 0.0625f - x_start, 0.0f);
    const float roi_h = fmaxf(roi[4] * 0.0625f - y_start, 0.0f);
    const float bin_h = roi_h / (float)(AH - 1);
    const float bin_w = roi_w / (float)(AW - 1);

    if (threadIdx.x == 0)
        s_base = ((int)roi[0]) * (Cc * HW);

    for (int i = threadIdx.x; i < NB; i += blockDim.x) {
        const int ph = i / AW;
        const int pw = i - ph * AW;
        float ys = y_start + (float)ph * bin_h;
        float xs = x_start + (float)pw * bin_w;
        ys = fminf(fmaxf(ys, 0.0f), (float)(Hh - 1));
        xs = fminf(fmaxf(xs, 0.0f), (float)(Ww - 1));
        const int y0 = (int)floorf(ys);
        const int x0 = (int)floorf(xs);
        const int y1 = min(y0 + 1, Hh - 1);
        const int x1 = min(x0 + 1, Ww - 1);
        const float wy = ys - (float)y0;
        const float wx = xs - (float)x0;
        s_off[i] = make_int4(y0 * Ww + x0, y0 * Ww + x1,
                             y1 * Ww + x0, y1 * Ww + x1);
        s_w[i]   = make_float4((1.0f - wy) * (1.0f - wx),
                               (1.0f - wy) * wx,
                               wy * (1.0f - wx),
                               wy * wx);
    }
    __syncthreads();

    const int base = s_base;
    float* __restrict__ outr = out + (size_t)r * (Cc * NB);
    const int jend = (c0 + 128) * NB;
    for (int j = c0 * NB + (int)threadIdx.x * 4; j < jend; j += 256 * 4) {
        const int c   = j / NB;
        const int bin = j - c * NB;
        const float* f = feat + base + c * HW;
        float4 v;
        {
            const int4 o = s_off[bin];     const float4 w = s_w[bin];
            v.x = w.x*f[o.x] + w.y*f[o.y] + w.z*f[o.z] + w.w*f[o.w];
        }
        {
            const int4 o = s_off[bin + 1]; const float4 w = s_w[bin + 1];
            v.y = w.x*f[o.x] + w.y*f[o.y] + w.z*f[o.z] + w.w*f[o.w];
        }
        {
            const int4 o = s_off[bin + 2]; const float4 w = s_w[bin + 2];
            v.z = w.x*f[o.x] + w.y*f[o.y] + w.z*f[o.z] + w.w*f[o.w];
        }
        {
            const int4 o = s_off[bin + 3]; const float4 w = s_w[bin + 3];
            v.w = w.x*f[o.x] + w.y*f[o.y] + w.z*f[o.z] + w.w*f[o.w];
        }
        *(float4*)(outr + j) = v;
    }
}

extern "C" void kernel_launch(void* const* d_in, const int* in_sizes, int n_in,
                              void* d_out, int out_size, void* d_ws, size_t ws_size,
                              hipStream_t stream)
{
    const float* feat = (const float*)d_in[0];
    const float* rois = (const float*)d_in[1];
    float*       out  = (float*)d_out;
    const int R = in_sizes[1] / 5;                       // 512

    const size_t need = (size_t)Nn * HW * Cc * sizeof(__half);  // 31.1 MB
    if (ws_size >= need) {
        __half* nhwc = (__half*)d_ws;
        dim3 tg((HW + 63) / 64, Cc / 64, Nn);            // (238, 8, 2)
        nchw_to_nhwc_f16<<<tg, 256, 0, stream>>>(feat, nhwc);
        dim3 mg(R, Cc / CPB);                            // (512, 2)
        roi_align_nhwc_f16<<<mg, 256, 0, stream>>>(nhwc, rois, out);
    } else {
        dim3 grid(R, Cc / 128);
        roi_align_nchw<<<grid, 256, 0, stream>>>(feat, rois, out);
    }
}